// Round 2
// baseline (732.613 us; speedup 1.0000x reference)
//
#include <hip/hip_runtime.h>
#include <math.h>

#define B_ 4
#define L_ 1024
#define D_ 1024
#define H_ 16
#define DH_ 64
#define M_ (B_*L_)   // 4096 rows

typedef _Float16 half8 __attribute__((ext_vector_type(8)));
typedef _Float16 half4 __attribute__((ext_vector_type(4)));
typedef float f32x4 __attribute__((ext_vector_type(4)));

#define MFMA16(a,b,c) __builtin_amdgcn_mfma_f32_16x16x32_f16(a, b, c, 0, 0, 0)

// ---------------- split kernels: fp32 -> scaled fp16 hi/lo pairs ----------------
__global__ __launch_bounds__(256) void split_x(const float* __restrict__ x,
                                               _Float16* __restrict__ xh,
                                               _Float16* __restrict__ xl) {
  const int i = blockIdx.x * 256 + threadIdx.x;   // 4 floats per thread
  float4 v = ((const float4*)x)[i];
  const float a0 = v.x * 16.f, a1 = v.y * 16.f, a2 = v.z * 16.f, a3 = v.w * 16.f;
  const _Float16 h0 = (_Float16)a0, h1 = (_Float16)a1, h2 = (_Float16)a2, h3 = (_Float16)a3;
  half4 hv, lv;
  hv[0] = h0; hv[1] = h1; hv[2] = h2; hv[3] = h3;
  lv[0] = (_Float16)(a0 - (float)h0);
  lv[1] = (_Float16)(a1 - (float)h1);
  lv[2] = (_Float16)(a2 - (float)h2);
  lv[3] = (_Float16)(a3 - (float)h3);
  ((half4*)xh)[i] = hv;
  ((half4*)xl)[i] = lv;
}

// W[k][n] -> transposed split Wh[n][k], Wl[n][k] (scale 512), via LDS tile.
__global__ __launch_bounds__(256) void split_wt(const float* __restrict__ W,
                                                _Float16* __restrict__ Wh,
                                                _Float16* __restrict__ Wl) {
  __shared__ float tile[64][65];
  const int t = threadIdx.x;
  const int tk = blockIdx.x & 15;
  const int tn = blockIdx.x >> 4;
  const int kr = t >> 2, ns = (t & 3) * 16;
  const float* src = W + (size_t)(tk * 64 + kr) * D_ + tn * 64 + ns;
  float4 v0 = ((const float4*)src)[0];
  float4 v1 = ((const float4*)src)[1];
  float4 v2 = ((const float4*)src)[2];
  float4 v3 = ((const float4*)src)[3];
  tile[ns + 0][kr] = v0.x;  tile[ns + 1][kr] = v0.y;  tile[ns + 2][kr] = v0.z;  tile[ns + 3][kr] = v0.w;
  tile[ns + 4][kr] = v1.x;  tile[ns + 5][kr] = v1.y;  tile[ns + 6][kr] = v1.z;  tile[ns + 7][kr] = v1.w;
  tile[ns + 8][kr] = v2.x;  tile[ns + 9][kr] = v2.y;  tile[ns + 10][kr] = v2.z; tile[ns + 11][kr] = v2.w;
  tile[ns + 12][kr] = v3.x; tile[ns + 13][kr] = v3.y; tile[ns + 14][kr] = v3.z; tile[ns + 15][kr] = v3.w;
  __syncthreads();
  const int nr = t >> 2, ks = (t & 3) * 16;
  const float* tr = &tile[nr][ks];
  half8 hv0, hv1, lv0, lv1;
#pragma unroll
  for (int i = 0; i < 8; i++) {
    const float s0 = tr[i] * 512.f;
    const float s1 = tr[i + 8] * 512.f;
    const _Float16 h0 = (_Float16)s0, h1 = (_Float16)s1;
    hv0[i] = h0; hv1[i] = h1;
    lv0[i] = (_Float16)(s0 - (float)h0);
    lv1[i] = (_Float16)(s1 - (float)h1);
  }
  _Float16* dh = Wh + (size_t)(tn * 64 + nr) * D_ + tk * 64 + ks;
  _Float16* dl = Wl + (size_t)(tn * 64 + nr) * D_ + tk * 64 + ks;
  *(half8*)dh = hv0; *(half8*)(dh + 8) = hv1;
  *(half8*)dl = lv0; *(half8*)(dl + 8) = lv1;
}

// ---------------- fp16x3 MFMA GEMM: C = (Ah+Al)(Bh+Bl)/8192 + bias ----------------
// 128x128 tile, BK=32, 4 waves (2x2), each wave 64x64 = 4x4 frags of 16x16x32.
// f16out: epilogue emits scale-16 f16 hi/lo split (for downstream MFMA consumers)
// instead of f32.
__device__ __forceinline__ void gemm_f16x3_body(
    const _Float16* __restrict__ Ah, const _Float16* __restrict__ Al,
    const _Float16* __restrict__ Bh, const _Float16* __restrict__ Bl,
    const float* __restrict__ bias, float* __restrict__ Cf,
    _Float16* __restrict__ Ch, _Float16* __restrict__ Cl, const bool f16out) {
  __shared__ __align__(16) _Float16 sA[2][2][128][32];
  __shared__ __align__(16) _Float16 sB[2][2][128][32];
  const int t = threadIdx.x;
  const int lane = t & 63;
  const int wid = t >> 6;
  const int bm = blockIdx.y * 128;
  const int bn = blockIdx.x * 128;

  const int m0 = t >> 2, sp0 = t & 3;
  const int sl0 = sp0 ^ ((m0 >> 1) & 3);
  const int m1 = m0 + 64;
  const _Float16* gA0h = Ah + (size_t)(bm + m0) * D_ + sl0 * 8;
  const _Float16* gA1h = Ah + (size_t)(bm + m1) * D_ + sl0 * 8;
  const _Float16* gA0l = Al + (size_t)(bm + m0) * D_ + sl0 * 8;
  const _Float16* gA1l = Al + (size_t)(bm + m1) * D_ + sl0 * 8;
  const _Float16* gB0h = Bh + (size_t)(bn + m0) * D_ + sl0 * 8;
  const _Float16* gB1h = Bh + (size_t)(bn + m1) * D_ + sl0 * 8;
  const _Float16* gB0l = Bl + (size_t)(bn + m0) * D_ + sl0 * 8;
  const _Float16* gB1l = Bl + (size_t)(bn + m1) * D_ + sl0 * 8;

  half8 rA0h = *(const half8*)(gA0h);
  half8 rA1h = *(const half8*)(gA1h);
  half8 rA0l = *(const half8*)(gA0l);
  half8 rA1l = *(const half8*)(gA1l);
  half8 rB0h = *(const half8*)(gB0h);
  half8 rB1h = *(const half8*)(gB1h);
  half8 rB0l = *(const half8*)(gB0l);
  half8 rB1l = *(const half8*)(gB1l);
  *(half8*)&sA[0][0][m0][sp0 * 8] = rA0h;
  *(half8*)&sA[0][0][m1][sp0 * 8] = rA1h;
  *(half8*)&sA[0][1][m0][sp0 * 8] = rA0l;
  *(half8*)&sA[0][1][m1][sp0 * 8] = rA1l;
  *(half8*)&sB[0][0][m0][sp0 * 8] = rB0h;
  *(half8*)&sB[0][0][m1][sp0 * 8] = rB1h;
  *(half8*)&sB[0][1][m0][sp0 * 8] = rB0l;
  *(half8*)&sB[0][1][m1][sp0 * 8] = rB1l;
  __syncthreads();

  f32x4 acc[4][4];
#pragma unroll
  for (int i = 0; i < 4; i++)
#pragma unroll
    for (int j = 0; j < 4; j++) acc[i][j] = {0.f, 0.f, 0.f, 0.f};

  const int wr = wid >> 1, wc = wid & 1;
  const int l15 = lane & 15;
  const int soff = ((lane >> 4) ^ ((l15 >> 1) & 3)) * 8;

  int p = 0;
  for (int k0 = 0; k0 < 1024; k0 += 32) {
    const bool more = (k0 + 32) < 1024;
    if (more) {
      const int kk = k0 + 32;
      rA0h = *(const half8*)(gA0h + kk);
      rA1h = *(const half8*)(gA1h + kk);
      rA0l = *(const half8*)(gA0l + kk);
      rA1l = *(const half8*)(gA1l + kk);
      rB0h = *(const half8*)(gB0h + kk);
      rB1h = *(const half8*)(gB1h + kk);
      rB0l = *(const half8*)(gB0l + kk);
      rB1l = *(const half8*)(gB1l + kk);
    }
    half8 bh[4], bl[4];
#pragma unroll
    for (int ni = 0; ni < 4; ni++) {
      const int rb = wc * 64 + ni * 16 + l15;
      bh[ni] = *(const half8*)&sB[p][0][rb][soff];
      bl[ni] = *(const half8*)&sB[p][1][rb][soff];
    }
#pragma unroll
    for (int mi = 0; mi < 4; mi++) {
      const int ra = wr * 64 + mi * 16 + l15;
      const half8 ah = *(const half8*)&sA[p][0][ra][soff];
      const half8 al = *(const half8*)&sA[p][1][ra][soff];
#pragma unroll
      for (int ni = 0; ni < 4; ni++) {
        acc[mi][ni] = MFMA16(ah, bh[ni], acc[mi][ni]);
        acc[mi][ni] = MFMA16(ah, bl[ni], acc[mi][ni]);
        acc[mi][ni] = MFMA16(al, bh[ni], acc[mi][ni]);
      }
    }
    if (more) {
      const int q = p ^ 1;
      *(half8*)&sA[q][0][m0][sp0 * 8] = rA0h;
      *(half8*)&sA[q][0][m1][sp0 * 8] = rA1h;
      *(half8*)&sA[q][1][m0][sp0 * 8] = rA0l;
      *(half8*)&sA[q][1][m1][sp0 * 8] = rA1l;
      *(half8*)&sB[q][0][m0][sp0 * 8] = rB0h;
      *(half8*)&sB[q][0][m1][sp0 * 8] = rB1h;
      *(half8*)&sB[q][1][m0][sp0 * 8] = rB0l;
      *(half8*)&sB[q][1][m1][sp0 * 8] = rB1l;
      __syncthreads();
      p = q;
    }
  }

  // epilogue: C row=(lane>>4)*4+reg, col=lane&15
  const float inv = 1.0f / 8192.0f;
  const int orow = bm + wr * 64 + (lane >> 4) * 4;
  const int ocol = bn + wc * 64 + l15;
#pragma unroll
  for (int ni = 0; ni < 4; ni++) {
    const int col = ocol + ni * 16;
    const float bv = bias[col];
#pragma unroll
    for (int mi = 0; mi < 4; mi++) {
      const f32x4 a = acc[mi][ni];
#pragma unroll
      for (int r = 0; r < 4; r++) {
        const size_t idx = (size_t)(orow + mi * 16 + r) * D_ + col;
        const float val = a[r] * inv + bv;
        if (f16out) {
          const float vs = val * 16.0f;            // scale 16 for attn MFMA
          const _Float16 hh = (_Float16)vs;
          Ch[idx] = hh;
          Cl[idx] = (_Float16)(vs - (float)hh);
        } else {
          Cf[idx] = val;
        }
      }
    }
  }
}

__global__ __launch_bounds__(256, 2) void gemm_qkv_f16(
    const _Float16* __restrict__ xh, const _Float16* __restrict__ xl,
    const _Float16* __restrict__ Whq, const _Float16* __restrict__ Wlq,
    const _Float16* __restrict__ Whk, const _Float16* __restrict__ Wlk,
    const _Float16* __restrict__ Whv, const _Float16* __restrict__ Wlv,
    const float* __restrict__ bq, const float* __restrict__ bk, const float* __restrict__ bv,
    _Float16* __restrict__ qh, _Float16* __restrict__ ql,
    _Float16* __restrict__ kh, _Float16* __restrict__ kl,
    float* __restrict__ vf) {
  const int z = blockIdx.z;
  const _Float16* Bh = (z == 0) ? Whq : (z == 1) ? Whk : Whv;
  const _Float16* Bl = (z == 0) ? Wlq : (z == 1) ? Wlk : Wlv;
  const float* bias = (z == 0) ? bq : (z == 1) ? bk : bv;
  if (z == 2) {
    gemm_f16x3_body(xh, xl, Bh, Bl, bias, vf, nullptr, nullptr, false);
  } else {
    _Float16* Ch = (z == 0) ? qh : kh;
    _Float16* Cl = (z == 0) ? ql : kl;
    gemm_f16x3_body(xh, xl, Bh, Bl, bias, nullptr, Ch, Cl, true);
  }
}

__global__ __launch_bounds__(256, 2) void gemm_out_f16(
    const _Float16* __restrict__ ah, const _Float16* __restrict__ al,
    const _Float16* __restrict__ bh, const _Float16* __restrict__ bl,
    const float* __restrict__ bias, float* __restrict__ C) {
  gemm_f16x3_body(ah, al, bh, bl, bias, C, nullptr, nullptr, false);
}

// ---------------- attention: MFMA QK^T into LDS scores + per-row top-k ----------------
// Block = 512 thr (8 waves), owns 32 q-rows x one (b,h), all 1024 keys.
// Phase 1: wave w computes S[0:32][w*128:(w+1)*128) via f16x3 MFMA (scale 1/2048),
//          stores to LDS S[32][1024] (XOR col-swizzle: writes 2-way, reads 2-way = free).
// Phase 2: wave w runs selection on rows w*4..w*4+3 (verbatim top-k logic).
#define SSWZ(row) (((row) & 7) << 2)

__global__ __launch_bounds__(512, 1) void attn_topk_mfma(
    const _Float16* __restrict__ qh, const _Float16* __restrict__ ql,
    const _Float16* __restrict__ kh, const _Float16* __restrict__ kl,
    const float* __restrict__ vf,
    _Float16* __restrict__ awh, _Float16* __restrict__ awl) {
  __shared__ float S[32][1024];   // 128 KB
  const int t = threadIdx.x;
  const int lane = t & 63;
  const int w = t >> 6;              // 0..7
  const int i0 = blockIdx.x * 32;    // q-row tile
  const int h = blockIdx.y;
  const int b = blockIdx.z;
  const size_t rowbase = (size_t)b * L_;
  const int l15 = lane & 15;
  const int kgrp = lane >> 4;        // 0..3

  // ---- A-frags: lane holds Q[i0 + rt*16 + l15][d = ks*32 + kgrp*8 .. +8)
  half8 Ahf[2][2], Alf[2][2];
#pragma unroll
  for (int rt = 0; rt < 2; rt++)
#pragma unroll
    for (int ks = 0; ks < 2; ks++) {
      const size_t off = (rowbase + i0 + rt * 16 + l15) * D_ + h * DH_ + ks * 32 + kgrp * 8;
      Ahf[rt][ks] = *(const half8*)(qh + off);
      Alf[rt][ks] = *(const half8*)(ql + off);
    }

  // ---- QK^T: wave w covers j in [w*128, w*128+128)
  const float sscale = 1.0f / 2048.0f;  // 1/(16*16) * 1/sqrt(64)
  for (int jt = 0; jt < 8; jt++) {
    const int j0 = w * 128 + jt * 16;
    const size_t koff = (rowbase + j0 + l15) * D_ + h * DH_ + kgrp * 8;
    const half8 Bh0 = *(const half8*)(kh + koff);
    const half8 Bh1 = *(const half8*)(kh + koff + 32);
    const half8 Bl0 = *(const half8*)(kl + koff);
    const half8 Bl1 = *(const half8*)(kl + koff + 32);
#pragma unroll
    for (int rt = 0; rt < 2; rt++) {
      f32x4 acc = {0.f, 0.f, 0.f, 0.f};
      acc = MFMA16(Ahf[rt][0], Bh0, acc);
      acc = MFMA16(Ahf[rt][1], Bh1, acc);
      acc = MFMA16(Ahf[rt][0], Bl0, acc);
      acc = MFMA16(Ahf[rt][1], Bl1, acc);
      acc = MFMA16(Alf[rt][0], Bh0, acc);
      acc = MFMA16(Alf[rt][1], Bh1, acc);
      const int srow = rt * 16 + kgrp * 4;
#pragma unroll
      for (int r = 0; r < 4; r++)
        S[srow + r][(j0 + l15) ^ SSWZ(srow + r)] = acc[r] * sscale;
    }
  }
  __syncthreads();

  // ---- selection: wave w owns rows w*4 .. w*4+3
  for (int rr = 0; rr < 4; rr++) {
    const int row = w * 4 + rr;
    const int swz = SSWZ(row);
    float sc[16];
#pragma unroll
    for (int u = 0; u < 16; u++) sc[u] = S[row][(u * 64 + lane) ^ swz];

    // ---- max
    float mx = sc[0];
#pragma unroll
    for (int u = 1; u < 16; u++) mx = fmaxf(mx, sc[u]);
#pragma unroll
    for (int off = 32; off >= 1; off >>= 1) mx = fmaxf(mx, __shfl_xor(mx, off, 64));

    // ---- bisection (window mx-16, 14 iters; exact descent below)
    float lo = mx - 16.f, hi = mx;
    for (int it = 0; it < 14; ++it) {
      float mid = 0.5f * (lo + hi);
      int cnt = 0;
#pragma unroll
      for (int u = 0; u < 16; u++) cnt += __popcll(__ballot(sc[u] >= mid));
      if (cnt >= 32) lo = mid; else hi = mid;
    }
    int cabove = 0;
#pragma unroll
    for (int u = 0; u < 16; u++) cabove += __popcll(__ballot(sc[u] >= hi));
    float v31 = hi;
    while (cabove < 32) {
      float nx = -INFINITY;
#pragma unroll
      for (int u = 0; u < 16; u++) nx = fmaxf(nx, (sc[u] < v31) ? sc[u] : -INFINITY);
#pragma unroll
      for (int off = 32; off >= 1; off >>= 1) nx = fmaxf(nx, __shfl_xor(nx, off, 64));
      int ceq = 0;
#pragma unroll
      for (int u = 0; u < 16; u++) ceq += __popcll(__ballot(sc[u] == nx));
      cabove += ceq;
      v31 = nx;
    }
    int c_eq = 0;
#pragma unroll
    for (int u = 0; u < 16; u++) c_eq += __popcll(__ballot(sc[u] == v31));
    const int c_gt = cabove - c_eq;
    const bool span = (cabove > 32);
    const int keep_eq = 32 - c_gt;
    float v32;
    if (span) {
      v32 = v31;
    } else {
      float nx = -INFINITY;
#pragma unroll
      for (int u = 0; u < 16; u++) nx = fmaxf(nx, (sc[u] < v31) ? sc[u] : -INFINITY);
#pragma unroll
      for (int off = 32; off >= 1; off >>= 1) nx = fmaxf(nx, __shfl_xor(nx, off, 64));
      v32 = nx;
    }
    const float tau = 0.5f * (v31 + v32);
    const float invbeta = 166666.67f;   // 1 / 6e-6

    float e[16];
#pragma unroll
    for (int u = 0; u < 16; u++) e[u] = __expf(sc[u] - mx);
    float z = 0.f;
#pragma unroll
    for (int u = 0; u < 16; u++) z += e[u];
#pragma unroll
    for (int off = 32; off >= 1; off >>= 1) z += __shfl_xor(z, off, 64);

    float fw[16];
    if (!span) {
#pragma unroll
      for (int u = 0; u < 16; u++) {
        float arg = (sc[u] - tau) * invbeta;
        fw[u] = (arg > 30.f) ? 1.f : ((arg < -30.f) ? 0.f : 1.f / (1.f + __expf(-arg)));
      }
    }

    const float cutoff = fminf(tau - 1.8e-4f, v31);
    const float* vcol = vf + rowbase * D_ + h * DH_ + lane;
    float Ssum = 0.f, acc = 0.f;
    int eq_seen = 0;
    for (int u = 0; u < 16; ++u) {
      unsigned long long mask = __ballot(sc[u] >= cutoff);
      while (mask) {
        int l2 = (int)__builtin_ctzll(mask);
        mask &= mask - 1;
        float e_ = __shfl(e[u], l2, 64);
        float f_;
        if (span) {
          float s_ = __shfl(sc[u], l2, 64);
          if (s_ > v31) f_ = 1.f;
          else if (s_ == v31) { f_ = (eq_seen < keep_eq) ? 1.f : 0.f; ++eq_seen; }
          else f_ = 0.f;
        } else {
          f_ = __shfl(fw[u], l2, 64);
        }
        float fe = f_ * e_;
        Ssum += fe;
        acc = fmaf(fe, vcol[(size_t)(u * 64 + l2) * D_], acc);
      }
    }
    const float o = acc / (Ssum + 1e-8f * z);
    const float os = o * 16.0f;                  // scale 16 for the f16x3 out-GEMM
    const _Float16 oh = (_Float16)os;
    const size_t oidx = (rowbase + i0 + row) * D_ + h * DH_ + lane;
    awh[oidx] = oh;
    awl[oidx] = (_Float16)(os - (float)oh);
  }
}

extern "C" void kernel_launch(void* const* d_in, const int* in_sizes, int n_in,
                              void* d_out, int out_size, void* d_ws, size_t ws_size,
                              hipStream_t stream) {
  const float* x  = (const float*)d_in[0];
  const float* Wq = (const float*)d_in[1];
  const float* bq = (const float*)d_in[2];
  const float* Wk = (const float*)d_in[3];
  const float* bk = (const float*)d_in[4];
  const float* Wv = (const float*)d_in[5];
  const float* bv = (const float*)d_in[6];
  const float* Wo = (const float*)d_in[7];
  const float* bo = (const float*)d_in[8];
  float* out = (float*)d_out;

  const size_t MD = (size_t)M_ * D_;   // 4M elements
  const size_t WD = (size_t)D_ * D_;   // 1M elements
  // ws layout (80 MB):
  //   [0,16MB)  qh+ql (f16)
  //   [16,32)   kh+kl (f16)
  //   [32,48)   vf (f32)
  //   [48,64)   xh+xl (f16) -> aliased as awh/awl after gemm_qkv
  //   [64,80)   Whq..Wlv (12 MB) + Who/Wlo (4 MB)
  float* slot0 = (float*)d_ws;
  float* slot1 = slot0 + MD;
  float* vf    = slot1 + MD;
  float* slot3 = vf + MD;
  float* slot4 = slot3 + MD;

  _Float16* qh = (_Float16*)slot0;  _Float16* ql = qh + MD;
  _Float16* kh = (_Float16*)slot1;  _Float16* kl = kh + MD;
  _Float16* xh = (_Float16*)slot3;  _Float16* xl = xh + MD;
  _Float16* awh = xh;               // alias: xh/xl dead after gemm_qkv
  _Float16* awl = xl;
  _Float16* Whq = (_Float16*)slot4;
  _Float16* Wlq = Whq + WD;
  _Float16* Whk = Wlq + WD;
  _Float16* Wlk = Whk + WD;
  _Float16* Whv = Wlk + WD;
  _Float16* Wlv = Whv + WD;
  _Float16* Who = Wlv + WD;
  _Float16* Wlo = Who + WD;

  dim3 b256(256);
  hipLaunchKernelGGL(split_x, dim3(4096), b256, 0, stream, x, xh, xl);
  hipLaunchKernelGGL(split_wt, dim3(256), b256, 0, stream, Wq, Whq, Wlq);
  hipLaunchKernelGGL(split_wt, dim3(256), b256, 0, stream, Wk, Whk, Wlk);
  hipLaunchKernelGGL(split_wt, dim3(256), b256, 0, stream, Wv, Whv, Wlv);
  hipLaunchKernelGGL(split_wt, dim3(256), b256, 0, stream, Wo, Who, Wlo);
  hipLaunchKernelGGL(gemm_qkv_f16, dim3(8, 32, 3), b256, 0, stream,
                     xh, xl, Whq, Wlq, Whk, Wlk, Whv, Wlv, bq, bk, bv,
                     qh, ql, kh, kl, vf);
  hipLaunchKernelGGL(attn_topk_mfma, dim3(32, 16, 4), dim3(512), 0, stream,
                     qh, ql, kh, kl, vf, awh, awl);
  hipLaunchKernelGGL(gemm_out_f16, dim3(8, 32), b256, 0, stream,
                     awh, awl, Who, Wlo, bo, out);
}

// Round 3
// 634.846 us; speedup vs baseline: 1.1540x; 1.1540x over previous
//
#include <hip/hip_runtime.h>
#include <math.h>

#define B_ 4
#define L_ 1024
#define D_ 1024
#define H_ 16
#define DH_ 64
#define M_ (B_*L_)   // 4096 rows

typedef _Float16 half8 __attribute__((ext_vector_type(8)));
typedef _Float16 half4 __attribute__((ext_vector_type(4)));
typedef float f32x4 __attribute__((ext_vector_type(4)));

#define MFMA16(a,b,c) __builtin_amdgcn_mfma_f32_16x16x32_f16(a, b, c, 0, 0, 0)

// ---------------- split kernels: fp32 -> scaled fp16 hi/lo pairs ----------------
__global__ __launch_bounds__(256) void split_x(const float* __restrict__ x,
                                               _Float16* __restrict__ xh,
                                               _Float16* __restrict__ xl) {
  const int i = blockIdx.x * 256 + threadIdx.x;   // 4 floats per thread
  float4 v = ((const float4*)x)[i];
  const float a0 = v.x * 16.f, a1 = v.y * 16.f, a2 = v.z * 16.f, a3 = v.w * 16.f;
  const _Float16 h0 = (_Float16)a0, h1 = (_Float16)a1, h2 = (_Float16)a2, h3 = (_Float16)a3;
  half4 hv, lv;
  hv[0] = h0; hv[1] = h1; hv[2] = h2; hv[3] = h3;
  lv[0] = (_Float16)(a0 - (float)h0);
  lv[1] = (_Float16)(a1 - (float)h1);
  lv[2] = (_Float16)(a2 - (float)h2);
  lv[3] = (_Float16)(a3 - (float)h3);
  ((half4*)xh)[i] = hv;
  ((half4*)xl)[i] = lv;
}

// W[k][n] -> transposed split Wh[n][k], Wl[n][k] (scale 512), via LDS tile.
__global__ __launch_bounds__(256) void split_wt(const float* __restrict__ W,
                                                _Float16* __restrict__ Wh,
                                                _Float16* __restrict__ Wl) {
  __shared__ float tile[64][65];
  const int t = threadIdx.x;
  const int tk = blockIdx.x & 15;
  const int tn = blockIdx.x >> 4;
  const int kr = t >> 2, ns = (t & 3) * 16;
  const float* src = W + (size_t)(tk * 64 + kr) * D_ + tn * 64 + ns;
  float4 v0 = ((const float4*)src)[0];
  float4 v1 = ((const float4*)src)[1];
  float4 v2 = ((const float4*)src)[2];
  float4 v3 = ((const float4*)src)[3];
  tile[ns + 0][kr] = v0.x;  tile[ns + 1][kr] = v0.y;  tile[ns + 2][kr] = v0.z;  tile[ns + 3][kr] = v0.w;
  tile[ns + 4][kr] = v1.x;  tile[ns + 5][kr] = v1.y;  tile[ns + 6][kr] = v1.z;  tile[ns + 7][kr] = v1.w;
  tile[ns + 8][kr] = v2.x;  tile[ns + 9][kr] = v2.y;  tile[ns + 10][kr] = v2.z; tile[ns + 11][kr] = v2.w;
  tile[ns + 12][kr] = v3.x; tile[ns + 13][kr] = v3.y; tile[ns + 14][kr] = v3.z; tile[ns + 15][kr] = v3.w;
  __syncthreads();
  const int nr = t >> 2, ks = (t & 3) * 16;
  const float* tr = &tile[nr][ks];
  half8 hv0, hv1, lv0, lv1;
#pragma unroll
  for (int i = 0; i < 8; i++) {
    const float s0 = tr[i] * 512.f;
    const float s1 = tr[i + 8] * 512.f;
    const _Float16 h0 = (_Float16)s0, h1 = (_Float16)s1;
    hv0[i] = h0; hv1[i] = h1;
    lv0[i] = (_Float16)(s0 - (float)h0);
    lv1[i] = (_Float16)(s1 - (float)h1);
  }
  _Float16* dh = Wh + (size_t)(tn * 64 + nr) * D_ + tk * 64 + ks;
  _Float16* dl = Wl + (size_t)(tn * 64 + nr) * D_ + tk * 64 + ks;
  *(half8*)dh = hv0; *(half8*)(dh + 8) = hv1;
  *(half8*)dl = lv0; *(half8*)(dl + 8) = lv1;
}

// ---------------- fp16x3 MFMA GEMM: C = (Ah+Al)(Bh+Bl)/8192 + bias ----------------
__device__ __forceinline__ void gemm_f16x3_body(
    const _Float16* __restrict__ Ah, const _Float16* __restrict__ Al,
    const _Float16* __restrict__ Bh, const _Float16* __restrict__ Bl,
    const float* __restrict__ bias, float* __restrict__ Cf,
    _Float16* __restrict__ Ch, _Float16* __restrict__ Cl, const bool f16out) {
  __shared__ __align__(16) _Float16 sA[2][2][128][32];
  __shared__ __align__(16) _Float16 sB[2][2][128][32];
  const int t = threadIdx.x;
  const int lane = t & 63;
  const int wid = t >> 6;
  const int bm = blockIdx.y * 128;
  const int bn = blockIdx.x * 128;

  const int m0 = t >> 2, sp0 = t & 3;
  const int sl0 = sp0 ^ ((m0 >> 1) & 3);
  const int m1 = m0 + 64;
  const _Float16* gA0h = Ah + (size_t)(bm + m0) * D_ + sl0 * 8;
  const _Float16* gA1h = Ah + (size_t)(bm + m1) * D_ + sl0 * 8;
  const _Float16* gA0l = Al + (size_t)(bm + m0) * D_ + sl0 * 8;
  const _Float16* gA1l = Al + (size_t)(bm + m1) * D_ + sl0 * 8;
  const _Float16* gB0h = Bh + (size_t)(bn + m0) * D_ + sl0 * 8;
  const _Float16* gB1h = Bh + (size_t)(bn + m1) * D_ + sl0 * 8;
  const _Float16* gB0l = Bl + (size_t)(bn + m0) * D_ + sl0 * 8;
  const _Float16* gB1l = Bl + (size_t)(bn + m1) * D_ + sl0 * 8;

  half8 rA0h = *(const half8*)(gA0h);
  half8 rA1h = *(const half8*)(gA1h);
  half8 rA0l = *(const half8*)(gA0l);
  half8 rA1l = *(const half8*)(gA1l);
  half8 rB0h = *(const half8*)(gB0h);
  half8 rB1h = *(const half8*)(gB1h);
  half8 rB0l = *(const half8*)(gB0l);
  half8 rB1l = *(const half8*)(gB1l);
  *(half8*)&sA[0][0][m0][sp0 * 8] = rA0h;
  *(half8*)&sA[0][0][m1][sp0 * 8] = rA1h;
  *(half8*)&sA[0][1][m0][sp0 * 8] = rA0l;
  *(half8*)&sA[0][1][m1][sp0 * 8] = rA1l;
  *(half8*)&sB[0][0][m0][sp0 * 8] = rB0h;
  *(half8*)&sB[0][0][m1][sp0 * 8] = rB1h;
  *(half8*)&sB[0][1][m0][sp0 * 8] = rB0l;
  *(half8*)&sB[0][1][m1][sp0 * 8] = rB1l;
  __syncthreads();

  f32x4 acc[4][4];
#pragma unroll
  for (int i = 0; i < 4; i++)
#pragma unroll
    for (int j = 0; j < 4; j++) acc[i][j] = {0.f, 0.f, 0.f, 0.f};

  const int wr = wid >> 1, wc = wid & 1;
  const int l15 = lane & 15;
  const int soff = ((lane >> 4) ^ ((l15 >> 1) & 3)) * 8;

  int p = 0;
  for (int k0 = 0; k0 < 1024; k0 += 32) {
    const bool more = (k0 + 32) < 1024;
    if (more) {
      const int kk = k0 + 32;
      rA0h = *(const half8*)(gA0h + kk);
      rA1h = *(const half8*)(gA1h + kk);
      rA0l = *(const half8*)(gA0l + kk);
      rA1l = *(const half8*)(gA1l + kk);
      rB0h = *(const half8*)(gB0h + kk);
      rB1h = *(const half8*)(gB1h + kk);
      rB0l = *(const half8*)(gB0l + kk);
      rB1l = *(const half8*)(gB1l + kk);
    }
    half8 bh[4], bl[4];
#pragma unroll
    for (int ni = 0; ni < 4; ni++) {
      const int rb = wc * 64 + ni * 16 + l15;
      bh[ni] = *(const half8*)&sB[p][0][rb][soff];
      bl[ni] = *(const half8*)&sB[p][1][rb][soff];
    }
#pragma unroll
    for (int mi = 0; mi < 4; mi++) {
      const int ra = wr * 64 + mi * 16 + l15;
      const half8 ah = *(const half8*)&sA[p][0][ra][soff];
      const half8 al = *(const half8*)&sA[p][1][ra][soff];
#pragma unroll
      for (int ni = 0; ni < 4; ni++) {
        acc[mi][ni] = MFMA16(ah, bh[ni], acc[mi][ni]);
        acc[mi][ni] = MFMA16(ah, bl[ni], acc[mi][ni]);
        acc[mi][ni] = MFMA16(al, bh[ni], acc[mi][ni]);
      }
    }
    if (more) {
      const int q = p ^ 1;
      *(half8*)&sA[q][0][m0][sp0 * 8] = rA0h;
      *(half8*)&sA[q][0][m1][sp0 * 8] = rA1h;
      *(half8*)&sA[q][1][m0][sp0 * 8] = rA0l;
      *(half8*)&sA[q][1][m1][sp0 * 8] = rA1l;
      *(half8*)&sB[q][0][m0][sp0 * 8] = rB0h;
      *(half8*)&sB[q][0][m1][sp0 * 8] = rB1h;
      *(half8*)&sB[q][1][m0][sp0 * 8] = rB0l;
      *(half8*)&sB[q][1][m1][sp0 * 8] = rB1l;
      __syncthreads();
      p = q;
    }
  }

  // epilogue: C row=(lane>>4)*4+reg, col=lane&15
  const float inv = 1.0f / 8192.0f;
  const int orow = bm + wr * 64 + (lane >> 4) * 4;
  const int ocol = bn + wc * 64 + l15;
#pragma unroll
  for (int ni = 0; ni < 4; ni++) {
    const int col = ocol + ni * 16;
    const float bv = bias[col];
#pragma unroll
    for (int mi = 0; mi < 4; mi++) {
      const f32x4 a = acc[mi][ni];
#pragma unroll
      for (int r = 0; r < 4; r++) {
        const size_t idx = (size_t)(orow + mi * 16 + r) * D_ + col;
        const float val = a[r] * inv + bv;
        if (f16out) {
          const float vs = val * 16.0f;            // scale 16 for attn MFMA
          const _Float16 hh = (_Float16)vs;
          Ch[idx] = hh;
          Cl[idx] = (_Float16)(vs - (float)hh);
        } else {
          Cf[idx] = val;
        }
      }
    }
  }
}

__global__ __launch_bounds__(256, 2) void gemm_qkv_f16(
    const _Float16* __restrict__ xh, const _Float16* __restrict__ xl,
    const _Float16* __restrict__ Whq, const _Float16* __restrict__ Wlq,
    const _Float16* __restrict__ Whk, const _Float16* __restrict__ Wlk,
    const _Float16* __restrict__ Whv, const _Float16* __restrict__ Wlv,
    const float* __restrict__ bq, const float* __restrict__ bk, const float* __restrict__ bv,
    _Float16* __restrict__ qh, _Float16* __restrict__ ql,
    _Float16* __restrict__ kh, _Float16* __restrict__ kl,
    float* __restrict__ vf) {
  const int z = blockIdx.z;
  const _Float16* Bh = (z == 0) ? Whq : (z == 1) ? Whk : Whv;
  const _Float16* Bl = (z == 0) ? Wlq : (z == 1) ? Wlk : Wlv;
  const float* bias = (z == 0) ? bq : (z == 1) ? bk : bv;
  if (z == 2) {
    gemm_f16x3_body(xh, xl, Bh, Bl, bias, vf, nullptr, nullptr, false);
  } else {
    _Float16* Ch = (z == 0) ? qh : kh;
    _Float16* Cl = (z == 0) ? ql : kl;
    gemm_f16x3_body(xh, xl, Bh, Bl, bias, nullptr, Ch, Cl, true);
  }
}

__global__ __launch_bounds__(256, 2) void gemm_out_f16(
    const _Float16* __restrict__ ah, const _Float16* __restrict__ al,
    const _Float16* __restrict__ bh, const _Float16* __restrict__ bl,
    const float* __restrict__ bias, float* __restrict__ C) {
  gemm_f16x3_body(ah, al, bh, bl, bias, C, nullptr, nullptr, false);
}

// ---------------- attention: MFMA QK^T + per-row top-k, occupancy-tuned ----------------
// Block = 256 thr (4 waves), owns 8 q-rows x one (b,h), all 1024 keys.
// S[8][1024] f32 = 32 KB -> ~5 blocks/CU (vs 1 at 128 KB in prev rev).
// MFMA A-tile duplicates the 8 rows (rows l15&7); kgrp>=2 lanes discard stores
// (2x matrix-pipe waste, hidden under other blocks' selection phases).
// Swizzle: store row r at col^(r<<2); two active row-groups (r, r+4) differ by
// XOR 16 -> disjoint 16-bank halves -> conflict-free; reads 2-way = free.
#define SSWZ(row) (((row) & 7) << 2)

__global__ __launch_bounds__(256, 5) void attn_topk_mfma(
    const _Float16* __restrict__ qh, const _Float16* __restrict__ ql,
    const _Float16* __restrict__ kh, const _Float16* __restrict__ kl,
    const float* __restrict__ vf,
    _Float16* __restrict__ awh, _Float16* __restrict__ awl) {
  __shared__ float S[8][1024];   // 32 KB
  const int t = threadIdx.x;
  const int lane = t & 63;
  const int w = t >> 6;              // 0..3
  const int i0 = blockIdx.x * 8;     // q-row tile
  const int h = blockIdx.y;
  const int b = blockIdx.z;
  const size_t rowbase = (size_t)b * L_;
  const int l15 = lane & 15;
  const int kgrp = lane >> 4;        // 0..3

  // ---- A-frags: rows i0 + (l15&7), duplicated over l15>=8
  half8 Ahf[2], Alf[2];
#pragma unroll
  for (int ks = 0; ks < 2; ks++) {
    const size_t off = (rowbase + i0 + (l15 & 7)) * D_ + h * DH_ + ks * 32 + kgrp * 8;
    Ahf[ks] = *(const half8*)(qh + off);
    Alf[ks] = *(const half8*)(ql + off);
  }

  // ---- QK^T: wave w covers j in [w*256, w*256+256)
  const float sscale = 1.0f / 2048.0f;  // 1/(16*16) * 1/sqrt(64)
  for (int jt = 0; jt < 16; jt++) {
    const int j0 = w * 256 + jt * 16;
    const size_t koff = (rowbase + j0 + l15) * D_ + h * DH_ + kgrp * 8;
    const half8 Bh0 = *(const half8*)(kh + koff);
    const half8 Bh1 = *(const half8*)(kh + koff + 32);
    const half8 Bl0 = *(const half8*)(kl + koff);
    const half8 Bl1 = *(const half8*)(kl + koff + 32);
    f32x4 acc = {0.f, 0.f, 0.f, 0.f};
    acc = MFMA16(Ahf[0], Bh0, acc);
    acc = MFMA16(Ahf[1], Bh1, acc);
    acc = MFMA16(Ahf[0], Bl0, acc);
    acc = MFMA16(Ahf[1], Bl1, acc);
    acc = MFMA16(Alf[0], Bh0, acc);
    acc = MFMA16(Alf[1], Bh1, acc);
    if (kgrp < 2) {
      const int srow = kgrp * 4;     // rows srow..srow+3 valid (0..7)
#pragma unroll
      for (int r = 0; r < 4; r++)
        S[srow + r][(j0 + l15) ^ SSWZ(srow + r)] = acc[r] * sscale;
    }
  }
  __syncthreads();

  // ---- selection: wave w owns rows 2w, 2w+1
  for (int rr = 0; rr < 2; rr++) {
    const int row = w * 2 + rr;
    const int swz = SSWZ(row);
    float sc[16];
#pragma unroll
    for (int u = 0; u < 16; u++) sc[u] = S[row][(u * 64 + lane) ^ swz];

    // ---- max
    float mx = sc[0];
#pragma unroll
    for (int u = 1; u < 16; u++) mx = fmaxf(mx, sc[u]);
#pragma unroll
    for (int off = 32; off >= 1; off >>= 1) mx = fmaxf(mx, __shfl_xor(mx, off, 64));

    // ---- bisection (window mx-16, 14 iters; exact descent below)
    float lo = mx - 16.f, hi = mx;
    for (int it = 0; it < 14; ++it) {
      float mid = 0.5f * (lo + hi);
      int cnt = 0;
#pragma unroll
      for (int u = 0; u < 16; u++) cnt += __popcll(__ballot(sc[u] >= mid));
      if (cnt >= 32) lo = mid; else hi = mid;
    }
    int cabove = 0;
#pragma unroll
    for (int u = 0; u < 16; u++) cabove += __popcll(__ballot(sc[u] >= hi));
    float v31 = hi;
    while (cabove < 32) {
      float nx = -INFINITY;
#pragma unroll
      for (int u = 0; u < 16; u++) nx = fmaxf(nx, (sc[u] < v31) ? sc[u] : -INFINITY);
#pragma unroll
      for (int off = 32; off >= 1; off >>= 1) nx = fmaxf(nx, __shfl_xor(nx, off, 64));
      int ceq = 0;
#pragma unroll
      for (int u = 0; u < 16; u++) ceq += __popcll(__ballot(sc[u] == nx));
      cabove += ceq;
      v31 = nx;
    }
    int c_eq = 0;
#pragma unroll
    for (int u = 0; u < 16; u++) c_eq += __popcll(__ballot(sc[u] == v31));
    const int c_gt = cabove - c_eq;
    const bool span = (cabove > 32);
    const int keep_eq = 32 - c_gt;
    float v32;
    if (span) {
      v32 = v31;
    } else {
      float nx = -INFINITY;
#pragma unroll
      for (int u = 0; u < 16; u++) nx = fmaxf(nx, (sc[u] < v31) ? sc[u] : -INFINITY);
#pragma unroll
      for (int off = 32; off >= 1; off >>= 1) nx = fmaxf(nx, __shfl_xor(nx, off, 64));
      v32 = nx;
    }
    const float tau = 0.5f * (v31 + v32);
    const float invbeta = 166666.67f;   // 1 / 6e-6

    float e[16];
#pragma unroll
    for (int u = 0; u < 16; u++) e[u] = __expf(sc[u] - mx);
    float z = 0.f;
#pragma unroll
    for (int u = 0; u < 16; u++) z += e[u];
#pragma unroll
    for (int off = 32; off >= 1; off >>= 1) z += __shfl_xor(z, off, 64);

    // fe[u] = f*e precomputed -> one shfl per selected key in the hot path
    float fe[16];
    if (!span) {
#pragma unroll
      for (int u = 0; u < 16; u++) {
        float arg = (sc[u] - tau) * invbeta;
        float fwv = (arg > 30.f) ? 1.f : ((arg < -30.f) ? 0.f : 1.f / (1.f + __expf(-arg)));
        fe[u] = fwv * e[u];
      }
    }

    const float cutoff = fminf(tau - 1.8e-4f, v31);
    const float* vcol = vf + rowbase * D_ + h * DH_ + lane;
    float Ssum = 0.f, acc = 0.f;
    int eq_seen = 0;
    for (int u = 0; u < 16; ++u) {
      unsigned long long mask = __ballot(sc[u] >= cutoff);
      while (mask) {
        int l2 = (int)__builtin_ctzll(mask);
        mask &= mask - 1;
        float fe_;
        if (span) {
          float e_ = __shfl(e[u], l2, 64);
          float s_ = __shfl(sc[u], l2, 64);
          float f_;
          if (s_ > v31) f_ = 1.f;
          else if (s_ == v31) { f_ = (eq_seen < keep_eq) ? 1.f : 0.f; ++eq_seen; }
          else f_ = 0.f;
          fe_ = f_ * e_;
        } else {
          fe_ = __shfl(fe[u], l2, 64);
        }
        Ssum += fe_;
        acc = fmaf(fe_, vcol[(size_t)(u * 64 + l2) * D_], acc);
      }
    }
    const float o = acc / (Ssum + 1e-8f * z);
    const float os = o * 16.0f;                  // scale 16 for the f16x3 out-GEMM
    const _Float16 oh = (_Float16)os;
    const size_t oidx = (rowbase + i0 + row) * D_ + h * DH_ + lane;
    awh[oidx] = oh;
    awl[oidx] = (_Float16)(os - (float)oh);
  }
}

extern "C" void kernel_launch(void* const* d_in, const int* in_sizes, int n_in,
                              void* d_out, int out_size, void* d_ws, size_t ws_size,
                              hipStream_t stream) {
  const float* x  = (const float*)d_in[0];
  const float* Wq = (const float*)d_in[1];
  const float* bq = (const float*)d_in[2];
  const float* Wk = (const float*)d_in[3];
  const float* bk = (const float*)d_in[4];
  const float* Wv = (const float*)d_in[5];
  const float* bv = (const float*)d_in[6];
  const float* Wo = (const float*)d_in[7];
  const float* bo = (const float*)d_in[8];
  float* out = (float*)d_out;

  const size_t MD = (size_t)M_ * D_;   // 4M elements
  const size_t WD = (size_t)D_ * D_;   // 1M elements
  float* slot0 = (float*)d_ws;
  float* slot1 = slot0 + MD;
  float* vf    = slot1 + MD;
  float* slot3 = vf + MD;
  float* slot4 = slot3 + MD;

  _Float16* qh = (_Float16*)slot0;  _Float16* ql = qh + MD;
  _Float16* kh = (_Float16*)slot1;  _Float16* kl = kh + MD;
  _Float16* xh = (_Float16*)slot3;  _Float16* xl = xh + MD;
  _Float16* awh = xh;               // alias: xh/xl dead after gemm_qkv
  _Float16* awl = xl;
  _Float16* Whq = (_Float16*)slot4;
  _Float16* Wlq = Whq + WD;
  _Float16* Whk = Wlq + WD;
  _Float16* Wlk = Whk + WD;
  _Float16* Whv = Wlk + WD;
  _Float16* Wlv = Whv + WD;
  _Float16* Who = Wlv + WD;
  _Float16* Wlo = Who + WD;

  dim3 b256(256);
  hipLaunchKernelGGL(split_x, dim3(4096), b256, 0, stream, x, xh, xl);
  hipLaunchKernelGGL(split_wt, dim3(256), b256, 0, stream, Wq, Whq, Wlq);
  hipLaunchKernelGGL(split_wt, dim3(256), b256, 0, stream, Wk, Whk, Wlk);
  hipLaunchKernelGGL(split_wt, dim3(256), b256, 0, stream, Wv, Whv, Wlv);
  hipLaunchKernelGGL(split_wt, dim3(256), b256, 0, stream, Wo, Who, Wlo);
  hipLaunchKernelGGL(gemm_qkv_f16, dim3(8, 32, 3), b256, 0, stream,
                     xh, xl, Whq, Wlq, Whk, Wlk, Whv, Wlv, bq, bk, bv,
                     qh, ql, kh, kl, vf);
  hipLaunchKernelGGL(attn_topk_mfma, dim3(128, 16, 4), b256, 0, stream,
                     qh, ql, kh, kl, vf, awh, awl);
  hipLaunchKernelGGL(gemm_out_f16, dim3(8, 32), b256, 0, stream,
                     awh, awl, Who, Wlo, bo, out);
}

// Round 4
// 603.986 us; speedup vs baseline: 1.2130x; 1.0511x over previous
//
#include <hip/hip_runtime.h>
#include <math.h>

#define B_ 4
#define L_ 1024
#define D_ 1024
#define H_ 16
#define DH_ 64
#define M_ (B_*L_)   // 4096 rows

typedef _Float16 half8 __attribute__((ext_vector_type(8)));
typedef _Float16 half4 __attribute__((ext_vector_type(4)));
typedef float f32x4 __attribute__((ext_vector_type(4)));

#define MFMA16(a,b,c) __builtin_amdgcn_mfma_f32_16x16x32_f16(a, b, c, 0, 0, 0)

// ---------------- split kernels: fp32 -> scaled fp16 hi/lo pairs ----------------
__global__ __launch_bounds__(256) void split_x(const float* __restrict__ x,
                                               _Float16* __restrict__ xh,
                                               _Float16* __restrict__ xl) {
  const int i = blockIdx.x * 256 + threadIdx.x;   // 4 floats per thread
  float4 v = ((const float4*)x)[i];
  const float a0 = v.x * 16.f, a1 = v.y * 16.f, a2 = v.z * 16.f, a3 = v.w * 16.f;
  const _Float16 h0 = (_Float16)a0, h1 = (_Float16)a1, h2 = (_Float16)a2, h3 = (_Float16)a3;
  half4 hv, lv;
  hv[0] = h0; hv[1] = h1; hv[2] = h2; hv[3] = h3;
  lv[0] = (_Float16)(a0 - (float)h0);
  lv[1] = (_Float16)(a1 - (float)h1);
  lv[2] = (_Float16)(a2 - (float)h2);
  lv[3] = (_Float16)(a3 - (float)h3);
  ((half4*)xh)[i] = hv;
  ((half4*)xl)[i] = lv;
}

// W[k][n] -> transposed split Wh[n][k], Wl[n][k] (scale 512), via LDS tile.
__global__ __launch_bounds__(256) void split_wt(const float* __restrict__ W,
                                                _Float16* __restrict__ Wh,
                                                _Float16* __restrict__ Wl) {
  __shared__ float tile[64][65];
  const int t = threadIdx.x;
  const int tk = blockIdx.x & 15;
  const int tn = blockIdx.x >> 4;
  const int kr = t >> 2, ns = (t & 3) * 16;
  const float* src = W + (size_t)(tk * 64 + kr) * D_ + tn * 64 + ns;
  float4 v0 = ((const float4*)src)[0];
  float4 v1 = ((const float4*)src)[1];
  float4 v2 = ((const float4*)src)[2];
  float4 v3 = ((const float4*)src)[3];
  tile[ns + 0][kr] = v0.x;  tile[ns + 1][kr] = v0.y;  tile[ns + 2][kr] = v0.z;  tile[ns + 3][kr] = v0.w;
  tile[ns + 4][kr] = v1.x;  tile[ns + 5][kr] = v1.y;  tile[ns + 6][kr] = v1.z;  tile[ns + 7][kr] = v1.w;
  tile[ns + 8][kr] = v2.x;  tile[ns + 9][kr] = v2.y;  tile[ns + 10][kr] = v2.z; tile[ns + 11][kr] = v2.w;
  tile[ns + 12][kr] = v3.x; tile[ns + 13][kr] = v3.y; tile[ns + 14][kr] = v3.z; tile[ns + 15][kr] = v3.w;
  __syncthreads();
  const int nr = t >> 2, ks = (t & 3) * 16;
  const float* tr = &tile[nr][ks];
  half8 hv0, hv1, lv0, lv1;
#pragma unroll
  for (int i = 0; i < 8; i++) {
    const float s0 = tr[i] * 512.f;
    const float s1 = tr[i + 8] * 512.f;
    const _Float16 h0 = (_Float16)s0, h1 = (_Float16)s1;
    hv0[i] = h0; hv1[i] = h1;
    lv0[i] = (_Float16)(s0 - (float)h0);
    lv1[i] = (_Float16)(s1 - (float)h1);
  }
  _Float16* dh = Wh + (size_t)(tn * 64 + nr) * D_ + tk * 64 + ks;
  _Float16* dl = Wl + (size_t)(tn * 64 + nr) * D_ + tk * 64 + ks;
  *(half8*)dh = hv0; *(half8*)(dh + 8) = hv1;
  *(half8*)dl = lv0; *(half8*)(dl + 8) = lv1;
}

// ---------------- fp16x3 MFMA GEMM: C = (Ah+Al)(Bh+Bl)/8192 + bias ----------------
__device__ __forceinline__ void gemm_f16x3_body(
    const _Float16* __restrict__ Ah, const _Float16* __restrict__ Al,
    const _Float16* __restrict__ Bh, const _Float16* __restrict__ Bl,
    const float* __restrict__ bias, float* __restrict__ Cf,
    _Float16* __restrict__ Ch, _Float16* __restrict__ Cl, const bool f16out) {
  __shared__ __align__(16) _Float16 sA[2][2][128][32];
  __shared__ __align__(16) _Float16 sB[2][2][128][32];
  const int t = threadIdx.x;
  const int lane = t & 63;
  const int wid = t >> 6;
  const int bm = blockIdx.y * 128;
  const int bn = blockIdx.x * 128;

  const int m0 = t >> 2, sp0 = t & 3;
  const int sl0 = sp0 ^ ((m0 >> 1) & 3);
  const int m1 = m0 + 64;
  const _Float16* gA0h = Ah + (size_t)(bm + m0) * D_ + sl0 * 8;
  const _Float16* gA1h = Ah + (size_t)(bm + m1) * D_ + sl0 * 8;
  const _Float16* gA0l = Al + (size_t)(bm + m0) * D_ + sl0 * 8;
  const _Float16* gA1l = Al + (size_t)(bm + m1) * D_ + sl0 * 8;
  const _Float16* gB0h = Bh + (size_t)(bn + m0) * D_ + sl0 * 8;
  const _Float16* gB1h = Bh + (size_t)(bn + m1) * D_ + sl0 * 8;
  const _Float16* gB0l = Bl + (size_t)(bn + m0) * D_ + sl0 * 8;
  const _Float16* gB1l = Bl + (size_t)(bn + m1) * D_ + sl0 * 8;

  half8 rA0h = *(const half8*)(gA0h);
  half8 rA1h = *(const half8*)(gA1h);
  half8 rA0l = *(const half8*)(gA0l);
  half8 rA1l = *(const half8*)(gA1l);
  half8 rB0h = *(const half8*)(gB0h);
  half8 rB1h = *(const half8*)(gB1h);
  half8 rB0l = *(const half8*)(gB0l);
  half8 rB1l = *(const half8*)(gB1l);
  *(half8*)&sA[0][0][m0][sp0 * 8] = rA0h;
  *(half8*)&sA[0][0][m1][sp0 * 8] = rA1h;
  *(half8*)&sA[0][1][m0][sp0 * 8] = rA0l;
  *(half8*)&sA[0][1][m1][sp0 * 8] = rA1l;
  *(half8*)&sB[0][0][m0][sp0 * 8] = rB0h;
  *(half8*)&sB[0][0][m1][sp0 * 8] = rB1h;
  *(half8*)&sB[0][1][m0][sp0 * 8] = rB0l;
  *(half8*)&sB[0][1][m1][sp0 * 8] = rB1l;
  __syncthreads();

  f32x4 acc[4][4];
#pragma unroll
  for (int i = 0; i < 4; i++)
#pragma unroll
    for (int j = 0; j < 4; j++) acc[i][j] = {0.f, 0.f, 0.f, 0.f};

  const int wr = wid >> 1, wc = wid & 1;
  const int l15 = lane & 15;
  const int soff = ((lane >> 4) ^ ((l15 >> 1) & 3)) * 8;

  int p = 0;
  for (int k0 = 0; k0 < 1024; k0 += 32) {
    const bool more = (k0 + 32) < 1024;
    if (more) {
      const int kk = k0 + 32;
      rA0h = *(const half8*)(gA0h + kk);
      rA1h = *(const half8*)(gA1h + kk);
      rA0l = *(const half8*)(gA0l + kk);
      rA1l = *(const half8*)(gA1l + kk);
      rB0h = *(const half8*)(gB0h + kk);
      rB1h = *(const half8*)(gB1h + kk);
      rB0l = *(const half8*)(gB0l + kk);
      rB1l = *(const half8*)(gB1l + kk);
    }
    half8 bh[4], bl[4];
#pragma unroll
    for (int ni = 0; ni < 4; ni++) {
      const int rb = wc * 64 + ni * 16 + l15;
      bh[ni] = *(const half8*)&sB[p][0][rb][soff];
      bl[ni] = *(const half8*)&sB[p][1][rb][soff];
    }
#pragma unroll
    for (int mi = 0; mi < 4; mi++) {
      const int ra = wr * 64 + mi * 16 + l15;
      const half8 ah = *(const half8*)&sA[p][0][ra][soff];
      const half8 al = *(const half8*)&sA[p][1][ra][soff];
#pragma unroll
      for (int ni = 0; ni < 4; ni++) {
        acc[mi][ni] = MFMA16(ah, bh[ni], acc[mi][ni]);
        acc[mi][ni] = MFMA16(ah, bl[ni], acc[mi][ni]);
        acc[mi][ni] = MFMA16(al, bh[ni], acc[mi][ni]);
      }
    }
    if (more) {
      const int q = p ^ 1;
      *(half8*)&sA[q][0][m0][sp0 * 8] = rA0h;
      *(half8*)&sA[q][0][m1][sp0 * 8] = rA1h;
      *(half8*)&sA[q][1][m0][sp0 * 8] = rA0l;
      *(half8*)&sA[q][1][m1][sp0 * 8] = rA1l;
      *(half8*)&sB[q][0][m0][sp0 * 8] = rB0h;
      *(half8*)&sB[q][0][m1][sp0 * 8] = rB1h;
      *(half8*)&sB[q][1][m0][sp0 * 8] = rB0l;
      *(half8*)&sB[q][1][m1][sp0 * 8] = rB1l;
      __syncthreads();
      p = q;
    }
  }

  // epilogue: C row=(lane>>4)*4+reg, col=lane&15
  const float inv = 1.0f / 8192.0f;
  const int orow = bm + wr * 64 + (lane >> 4) * 4;
  const int ocol = bn + wc * 64 + l15;
#pragma unroll
  for (int ni = 0; ni < 4; ni++) {
    const int col = ocol + ni * 16;
    const float bv = bias[col];
#pragma unroll
    for (int mi = 0; mi < 4; mi++) {
      const f32x4 a = acc[mi][ni];
#pragma unroll
      for (int r = 0; r < 4; r++) {
        const size_t idx = (size_t)(orow + mi * 16 + r) * D_ + col;
        const float val = a[r] * inv + bv;
        if (f16out) {
          const float vs = val * 16.0f;            // scale 16 for attn MFMA
          const _Float16 hh = (_Float16)vs;
          Ch[idx] = hh;
          Cl[idx] = (_Float16)(vs - (float)hh);
        } else {
          Cf[idx] = val;
        }
      }
    }
  }
}

__global__ __launch_bounds__(256, 2) void gemm_qkv_f16(
    const _Float16* __restrict__ xh, const _Float16* __restrict__ xl,
    const _Float16* __restrict__ Whq, const _Float16* __restrict__ Wlq,
    const _Float16* __restrict__ Whk, const _Float16* __restrict__ Wlk,
    const _Float16* __restrict__ Whv, const _Float16* __restrict__ Wlv,
    const float* __restrict__ bq, const float* __restrict__ bk, const float* __restrict__ bv,
    _Float16* __restrict__ qh, _Float16* __restrict__ ql,
    _Float16* __restrict__ kh, _Float16* __restrict__ kl,
    float* __restrict__ vf) {
  const int z = blockIdx.z;
  const _Float16* Bh = (z == 0) ? Whq : (z == 1) ? Whk : Whv;
  const _Float16* Bl = (z == 0) ? Wlq : (z == 1) ? Wlk : Wlv;
  const float* bias = (z == 0) ? bq : (z == 1) ? bk : bv;
  if (z == 2) {
    gemm_f16x3_body(xh, xl, Bh, Bl, bias, vf, nullptr, nullptr, false);
  } else {
    _Float16* Ch = (z == 0) ? qh : kh;
    _Float16* Cl = (z == 0) ? ql : kl;
    gemm_f16x3_body(xh, xl, Bh, Bl, bias, nullptr, Ch, Cl, true);
  }
}

__global__ __launch_bounds__(256, 2) void gemm_out_f16(
    const _Float16* __restrict__ ah, const _Float16* __restrict__ al,
    const _Float16* __restrict__ bh, const _Float16* __restrict__ bl,
    const float* __restrict__ bias, float* __restrict__ C) {
  gemm_f16x3_body(ah, al, bh, bl, bias, C, nullptr, nullptr, false);
}

// ---------------- attention: MFMA QK^T + per-row top-k, latency-optimized ----------------
// Block = 512 thr (8 waves), owns 8 q-rows x one (b,h). One row per wave.
// S[8][1024] f32 = 32 KB + 4.5 KB cand lists -> 4 blocks/CU -> up to 32 waves/CU.
// Selection: identical bisection/descent numerics; V-gather restructured:
// candidates compacted to LDS (ballot prefix), then chunks of 8 INDEPENDENT
// loads (one vmcnt wait per 8 keys instead of per key, no per-key shfl).
// Span / >64-candidate rows use the exact original serial loop.
#define SSWZ(row) (((row) & 7) << 2)

__global__ __launch_bounds__(512, 8) void attn_topk_mfma(
    const _Float16* __restrict__ qh, const _Float16* __restrict__ ql,
    const _Float16* __restrict__ kh, const _Float16* __restrict__ kl,
    const float* __restrict__ vf,
    _Float16* __restrict__ awh, _Float16* __restrict__ awl) {
  __shared__ float S[8][1024];   // 32 KB
  __shared__ int   cidx[8][64];  // 2 KB   per-row candidate j list
  __shared__ float cfe[8][64];   // 2 KB   per-row candidate fe list
  const int t = threadIdx.x;
  const int lane = t & 63;
  const int w = t >> 6;              // 0..7, one q-row per wave
  const int i0 = blockIdx.x * 8;     // q-row tile
  const int h = blockIdx.y;
  const int b = blockIdx.z;
  const size_t rowbase = (size_t)b * L_;
  const int l15 = lane & 15;
  const int kgrp = lane >> 4;        // 0..3

  // ---- A-frags: rows i0 + (l15&7), duplicated over l15>=8
  half8 Ahf[2], Alf[2];
#pragma unroll
  for (int ks = 0; ks < 2; ks++) {
    const size_t off = (rowbase + i0 + (l15 & 7)) * D_ + h * DH_ + ks * 32 + kgrp * 8;
    Ahf[ks] = *(const half8*)(qh + off);
    Alf[ks] = *(const half8*)(ql + off);
  }

  // ---- QK^T: wave w covers j in [w*128, w*128+128)
  const float sscale = 1.0f / 2048.0f;  // 1/(16*16) * 1/sqrt(64)
  for (int jt = 0; jt < 8; jt++) {
    const int j0 = w * 128 + jt * 16;
    const size_t koff = (rowbase + j0 + l15) * D_ + h * DH_ + kgrp * 8;
    const half8 Bh0 = *(const half8*)(kh + koff);
    const half8 Bh1 = *(const half8*)(kh + koff + 32);
    const half8 Bl0 = *(const half8*)(kl + koff);
    const half8 Bl1 = *(const half8*)(kl + koff + 32);
    f32x4 acc = {0.f, 0.f, 0.f, 0.f};
    acc = MFMA16(Ahf[0], Bh0, acc);
    acc = MFMA16(Ahf[1], Bh1, acc);
    acc = MFMA16(Ahf[0], Bl0, acc);
    acc = MFMA16(Ahf[1], Bl1, acc);
    acc = MFMA16(Alf[0], Bh0, acc);
    acc = MFMA16(Alf[1], Bh1, acc);
    if (kgrp < 2) {
      const int srow = kgrp * 4;     // rows srow..srow+3 valid (0..7)
#pragma unroll
      for (int r = 0; r < 4; r++)
        S[srow + r][(j0 + l15) ^ SSWZ(srow + r)] = acc[r] * sscale;
    }
  }
  __syncthreads();

  // ---- selection: wave w owns row w
  const int row = w;
  const int swz = SSWZ(row);
  float sc[16];
#pragma unroll
  for (int u = 0; u < 16; u++) sc[u] = S[row][(u * 64 + lane) ^ swz];

  // ---- max
  float mx = sc[0];
#pragma unroll
  for (int u = 1; u < 16; u++) mx = fmaxf(mx, sc[u]);
#pragma unroll
  for (int off = 32; off >= 1; off >>= 1) mx = fmaxf(mx, __shfl_xor(mx, off, 64));

  // ---- bisection (window mx-16, 14 iters; exact descent below)
  float lo = mx - 16.f, hi = mx;
  for (int it = 0; it < 14; ++it) {
    float mid = 0.5f * (lo + hi);
    int cnt = 0;
#pragma unroll
    for (int u = 0; u < 16; u++) cnt += __popcll(__ballot(sc[u] >= mid));
    if (cnt >= 32) lo = mid; else hi = mid;
  }
  int cabove = 0;
#pragma unroll
  for (int u = 0; u < 16; u++) cabove += __popcll(__ballot(sc[u] >= hi));
  float v31 = hi;
  while (cabove < 32) {
    float nx = -INFINITY;
#pragma unroll
    for (int u = 0; u < 16; u++) nx = fmaxf(nx, (sc[u] < v31) ? sc[u] : -INFINITY);
#pragma unroll
    for (int off = 32; off >= 1; off >>= 1) nx = fmaxf(nx, __shfl_xor(nx, off, 64));
    int ceq = 0;
#pragma unroll
    for (int u = 0; u < 16; u++) ceq += __popcll(__ballot(sc[u] == nx));
    cabove += ceq;
    v31 = nx;
  }
  int c_eq = 0;
#pragma unroll
  for (int u = 0; u < 16; u++) c_eq += __popcll(__ballot(sc[u] == v31));
  const int c_gt = cabove - c_eq;
  const bool span = (cabove > 32);
  const int keep_eq = 32 - c_gt;
  float v32;
  if (span) {
    v32 = v31;
  } else {
    float nx = -INFINITY;
#pragma unroll
    for (int u = 0; u < 16; u++) nx = fmaxf(nx, (sc[u] < v31) ? sc[u] : -INFINITY);
#pragma unroll
    for (int off = 32; off >= 1; off >>= 1) nx = fmaxf(nx, __shfl_xor(nx, off, 64));
    v32 = nx;
  }
  const float tau = 0.5f * (v31 + v32);
  const float invbeta = 166666.67f;   // 1 / 6e-6

  float e[16];
#pragma unroll
  for (int u = 0; u < 16; u++) e[u] = __expf(sc[u] - mx);
  float z = 0.f;
#pragma unroll
  for (int u = 0; u < 16; u++) z += e[u];
#pragma unroll
  for (int off = 32; off >= 1; off >>= 1) z += __shfl_xor(z, off, 64);

  // fe[u] = f*e; sigmoid only when some score is inside the transition band
  // (|sc-tau| <= ~1.8e-4). Outside the band the sigmoid saturates exactly to
  // 0/1, so fe = (sc > tau) ? e : 0 is bit-identical to the original.
  float fe[16];
  if (!span) {
    int inband = 0;
#pragma unroll
    for (int u = 0; u < 16; u++)
      inband |= (fabsf(sc[u] - tau) <= 1.81e-4f) ? 1 : 0;
    if (__ballot(inband) != 0ull) {
#pragma unroll
      for (int u = 0; u < 16; u++) {
        float arg = (sc[u] - tau) * invbeta;
        float fwv = (arg > 30.f) ? 1.f : ((arg < -30.f) ? 0.f : 1.f / (1.f + __expf(-arg)));
        fe[u] = fwv * e[u];
      }
    } else {
#pragma unroll
      for (int u = 0; u < 16; u++) fe[u] = (sc[u] > tau) ? e[u] : 0.f;
    }
  }

  const float cutoff = fminf(tau - 1.8e-4f, v31);
  const float* vcol = vf + rowbase * D_ + h * DH_ + lane;
  float o;
  bool fast = false;
  if (!span) {
    // ---- compact candidates (j, fe) into LDS via ballot prefix
    int run = 0;
    float psum = 0.f;
#pragma unroll
    for (int u = 0; u < 16; u++) {
      unsigned long long m = __ballot(sc[u] >= cutoff);
      if (sc[u] >= cutoff) {
        int pos = run + (int)__popcll(m & ((1ull << lane) - 1ull));
        if (pos < 64) { cidx[w][pos] = u * 64 + lane; cfe[w][pos] = fe[u]; }
        psum += fe[u];
      }
      run += (int)__popcll(m);
    }
    if (run <= 64) {
      fast = true;
      float Ssum = psum;
#pragma unroll
      for (int off = 32; off >= 1; off >>= 1) Ssum += __shfl_xor(Ssum, off, 64);
      const int npad = (run + 7) & ~7;
      if (lane < npad - run) { cidx[w][run + lane] = 0; cfe[w][run + lane] = 0.f; }
      float acc = 0.f;
      for (int c = 0; c < npad; c += 8) {
        int jx[8]; float fx[8]; float vv[8];
#pragma unroll
        for (int i = 0; i < 8; i++) { jx[i] = cidx[w][c + i]; fx[i] = cfe[w][c + i]; }
#pragma unroll
        for (int i = 0; i < 8; i++) vv[i] = vcol[(size_t)jx[i] * D_];
#pragma unroll
        for (int i = 0; i < 8; i++) acc = fmaf(fx[i], vv[i], acc);
      }
      o = acc / (Ssum + 1e-8f * z);
    }
  }
  if (!fast) {
    // ---- exact original serial path (span ties / candidate overflow)
    float Ssum = 0.f, acc = 0.f;
    int eq_seen = 0;
    for (int u = 0; u < 16; ++u) {
      unsigned long long mask = __ballot(sc[u] >= cutoff);
      while (mask) {
        int l2 = (int)__builtin_ctzll(mask);
        mask &= mask - 1;
        float fe_;
        if (span) {
          float e_ = __shfl(e[u], l2, 64);
          float s_ = __shfl(sc[u], l2, 64);
          float f_;
          if (s_ > v31) f_ = 1.f;
          else if (s_ == v31) { f_ = (eq_seen < keep_eq) ? 1.f : 0.f; ++eq_seen; }
          else f_ = 0.f;
          fe_ = f_ * e_;
        } else {
          fe_ = __shfl(fe[u], l2, 64);
        }
        Ssum += fe_;
        acc = fmaf(fe_, vcol[(size_t)(u * 64 + l2) * D_], acc);
      }
    }
    o = acc / (Ssum + 1e-8f * z);
  }

  const float os = o * 16.0f;                  // scale 16 for the f16x3 out-GEMM
  const _Float16 oh = (_Float16)os;
  const size_t oidx = (rowbase + i0 + row) * D_ + h * DH_ + lane;
  awh[oidx] = oh;
  awl[oidx] = (_Float16)(os - (float)oh);
}

extern "C" void kernel_launch(void* const* d_in, const int* in_sizes, int n_in,
                              void* d_out, int out_size, void* d_ws, size_t ws_size,
                              hipStream_t stream) {
  const float* x  = (const float*)d_in[0];
  const float* Wq = (const float*)d_in[1];
  const float* bq = (const float*)d_in[2];
  const float* Wk = (const float*)d_in[3];
  const float* bk = (const float*)d_in[4];
  const float* Wv = (const float*)d_in[5];
  const float* bv = (const float*)d_in[6];
  const float* Wo = (const float*)d_in[7];
  const float* bo = (const float*)d_in[8];
  float* out = (float*)d_out;

  const size_t MD = (size_t)M_ * D_;   // 4M elements
  const size_t WD = (size_t)D_ * D_;   // 1M elements
  float* slot0 = (float*)d_ws;
  float* slot1 = slot0 + MD;
  float* vf    = slot1 + MD;
  float* slot3 = vf + MD;
  float* slot4 = slot3 + MD;

  _Float16* qh = (_Float16*)slot0;  _Float16* ql = qh + MD;
  _Float16* kh = (_Float16*)slot1;  _Float16* kl = kh + MD;
  _Float16* xh = (_Float16*)slot3;  _Float16* xl = xh + MD;
  _Float16* awh = xh;               // alias: xh/xl dead after gemm_qkv
  _Float16* awl = xl;
  _Float16* Whq = (_Float16*)slot4;
  _Float16* Wlq = Whq + WD;
  _Float16* Whk = Wlq + WD;
  _Float16* Wlk = Whk + WD;
  _Float16* Whv = Wlk + WD;
  _Float16* Wlv = Whv + WD;
  _Float16* Who = Wlv + WD;
  _Float16* Wlo = Who + WD;

  dim3 b256(256);
  hipLaunchKernelGGL(split_x, dim3(4096), b256, 0, stream, x, xh, xl);
  hipLaunchKernelGGL(split_wt, dim3(256), b256, 0, stream, Wq, Whq, Wlq);
  hipLaunchKernelGGL(split_wt, dim3(256), b256, 0, stream, Wk, Whk, Wlk);
  hipLaunchKernelGGL(split_wt, dim3(256), b256, 0, stream, Wv, Whv, Wlv);
  hipLaunchKernelGGL(split_wt, dim3(256), b256, 0, stream, Wo, Who, Wlo);
  hipLaunchKernelGGL(gemm_qkv_f16, dim3(8, 32, 3), b256, 0, stream,
                     xh, xl, Whq, Wlq, Whk, Wlk, Whv, Wlv, bq, bk, bv,
                     qh, ql, kh, kl, vf);
  hipLaunchKernelGGL(attn_topk_mfma, dim3(128, 16, 4), dim3(512), 0, stream,
                     qh, ql, kh, kl, vf, awh, awl);
  hipLaunchKernelGGL(gemm_out_f16, dim3(8, 32), b256, 0, stream,
                     awh, awl, Who, Wlo, bo, out);
}

// Round 5
// 500.609 us; speedup vs baseline: 1.4634x; 1.2065x over previous
//
#include <hip/hip_runtime.h>
#include <math.h>

#define B_ 4
#define L_ 1024
#define D_ 1024
#define H_ 16
#define DH_ 64
#define M_ (B_*L_)   // 4096 rows

typedef _Float16 half8 __attribute__((ext_vector_type(8)));
typedef _Float16 half4 __attribute__((ext_vector_type(4)));
typedef float f32x4 __attribute__((ext_vector_type(4)));

#define MFMA16(a,b,c) __builtin_amdgcn_mfma_f32_16x16x32_f16(a, b, c, 0, 0, 0)

// ---------------- split kernels: fp32 -> scaled fp16 hi/lo pairs ----------------
__global__ __launch_bounds__(256) void split_x(const float* __restrict__ x,
                                               _Float16* __restrict__ xh,
                                               _Float16* __restrict__ xl) {
  const int i = blockIdx.x * 256 + threadIdx.x;   // 4 floats per thread
  float4 v = ((const float4*)x)[i];
  const float a0 = v.x * 16.f, a1 = v.y * 16.f, a2 = v.z * 16.f, a3 = v.w * 16.f;
  const _Float16 h0 = (_Float16)a0, h1 = (_Float16)a1, h2 = (_Float16)a2, h3 = (_Float16)a3;
  half4 hv, lv;
  hv[0] = h0; hv[1] = h1; hv[2] = h2; hv[3] = h3;
  lv[0] = (_Float16)(a0 - (float)h0);
  lv[1] = (_Float16)(a1 - (float)h1);
  lv[2] = (_Float16)(a2 - (float)h2);
  lv[3] = (_Float16)(a3 - (float)h3);
  ((half4*)xh)[i] = hv;
  ((half4*)xl)[i] = lv;
}

// W[k][n] -> transposed split Wh[n][k], Wl[n][k] (scale 512), via LDS tile.
__global__ __launch_bounds__(256) void split_wt(const float* __restrict__ W,
                                                _Float16* __restrict__ Wh,
                                                _Float16* __restrict__ Wl) {
  __shared__ float tile[64][65];
  const int t = threadIdx.x;
  const int tk = blockIdx.x & 15;
  const int tn = blockIdx.x >> 4;
  const int kr = t >> 2, ns = (t & 3) * 16;
  const float* src = W + (size_t)(tk * 64 + kr) * D_ + tn * 64 + ns;
  float4 v0 = ((const float4*)src)[0];
  float4 v1 = ((const float4*)src)[1];
  float4 v2 = ((const float4*)src)[2];
  float4 v3 = ((const float4*)src)[3];
  tile[ns + 0][kr] = v0.x;  tile[ns + 1][kr] = v0.y;  tile[ns + 2][kr] = v0.z;  tile[ns + 3][kr] = v0.w;
  tile[ns + 4][kr] = v1.x;  tile[ns + 5][kr] = v1.y;  tile[ns + 6][kr] = v1.z;  tile[ns + 7][kr] = v1.w;
  tile[ns + 8][kr] = v2.x;  tile[ns + 9][kr] = v2.y;  tile[ns + 10][kr] = v2.z; tile[ns + 11][kr] = v2.w;
  tile[ns + 12][kr] = v3.x; tile[ns + 13][kr] = v3.y; tile[ns + 14][kr] = v3.z; tile[ns + 15][kr] = v3.w;
  __syncthreads();
  const int nr = t >> 2, ks = (t & 3) * 16;
  const float* tr = &tile[nr][ks];
  half8 hv0, hv1, lv0, lv1;
#pragma unroll
  for (int i = 0; i < 8; i++) {
    const float s0 = tr[i] * 512.f;
    const float s1 = tr[i + 8] * 512.f;
    const _Float16 h0 = (_Float16)s0, h1 = (_Float16)s1;
    hv0[i] = h0; hv1[i] = h1;
    lv0[i] = (_Float16)(s0 - (float)h0);
    lv1[i] = (_Float16)(s1 - (float)h1);
  }
  _Float16* dh = Wh + (size_t)(tn * 64 + nr) * D_ + tk * 64 + ks;
  _Float16* dl = Wl + (size_t)(tn * 64 + nr) * D_ + tk * 64 + ks;
  *(half8*)dh = hv0; *(half8*)(dh + 8) = hv1;
  *(half8*)dl = lv0; *(half8*)(dl + 8) = lv1;
}

// ---------------- fp16x3 MFMA GEMM: C = (Ah+Al)(Bh+Bl)/8192 + bias ----------------
__device__ __forceinline__ void gemm_f16x3_body(
    const _Float16* __restrict__ Ah, const _Float16* __restrict__ Al,
    const _Float16* __restrict__ Bh, const _Float16* __restrict__ Bl,
    const float* __restrict__ bias, float* __restrict__ Cf,
    _Float16* __restrict__ Ch, _Float16* __restrict__ Cl, const bool f16out) {
  __shared__ __align__(16) _Float16 sA[2][2][128][32];
  __shared__ __align__(16) _Float16 sB[2][2][128][32];
  const int t = threadIdx.x;
  const int lane = t & 63;
  const int wid = t >> 6;
  const int bm = blockIdx.y * 128;
  const int bn = blockIdx.x * 128;

  const int m0 = t >> 2, sp0 = t & 3;
  const int sl0 = sp0 ^ ((m0 >> 1) & 3);
  const int m1 = m0 + 64;
  const _Float16* gA0h = Ah + (size_t)(bm + m0) * D_ + sl0 * 8;
  const _Float16* gA1h = Ah + (size_t)(bm + m1) * D_ + sl0 * 8;
  const _Float16* gA0l = Al + (size_t)(bm + m0) * D_ + sl0 * 8;
  const _Float16* gA1l = Al + (size_t)(bm + m1) * D_ + sl0 * 8;
  const _Float16* gB0h = Bh + (size_t)(bn + m0) * D_ + sl0 * 8;
  const _Float16* gB1h = Bh + (size_t)(bn + m1) * D_ + sl0 * 8;
  const _Float16* gB0l = Bl + (size_t)(bn + m0) * D_ + sl0 * 8;
  const _Float16* gB1l = Bl + (size_t)(bn + m1) * D_ + sl0 * 8;

  half8 rA0h = *(const half8*)(gA0h);
  half8 rA1h = *(const half8*)(gA1h);
  half8 rA0l = *(const half8*)(gA0l);
  half8 rA1l = *(const half8*)(gA1l);
  half8 rB0h = *(const half8*)(gB0h);
  half8 rB1h = *(const half8*)(gB1h);
  half8 rB0l = *(const half8*)(gB0l);
  half8 rB1l = *(const half8*)(gB1l);
  *(half8*)&sA[0][0][m0][sp0 * 8] = rA0h;
  *(half8*)&sA[0][0][m1][sp0 * 8] = rA1h;
  *(half8*)&sA[0][1][m0][sp0 * 8] = rA0l;
  *(half8*)&sA[0][1][m1][sp0 * 8] = rA1l;
  *(half8*)&sB[0][0][m0][sp0 * 8] = rB0h;
  *(half8*)&sB[0][0][m1][sp0 * 8] = rB1h;
  *(half8*)&sB[0][1][m0][sp0 * 8] = rB0l;
  *(half8*)&sB[0][1][m1][sp0 * 8] = rB1l;
  __syncthreads();

  f32x4 acc[4][4];
#pragma unroll
  for (int i = 0; i < 4; i++)
#pragma unroll
    for (int j = 0; j < 4; j++) acc[i][j] = {0.f, 0.f, 0.f, 0.f};

  const int wr = wid >> 1, wc = wid & 1;
  const int l15 = lane & 15;
  const int soff = ((lane >> 4) ^ ((l15 >> 1) & 3)) * 8;

  int p = 0;
  for (int k0 = 0; k0 < 1024; k0 += 32) {
    const bool more = (k0 + 32) < 1024;
    if (more) {
      const int kk = k0 + 32;
      rA0h = *(const half8*)(gA0h + kk);
      rA1h = *(const half8*)(gA1h + kk);
      rA0l = *(const half8*)(gA0l + kk);
      rA1l = *(const half8*)(gA1l + kk);
      rB0h = *(const half8*)(gB0h + kk);
      rB1h = *(const half8*)(gB1h + kk);
      rB0l = *(const half8*)(gB0l + kk);
      rB1l = *(const half8*)(gB1l + kk);
    }
    half8 bh[4], bl[4];
#pragma unroll
    for (int ni = 0; ni < 4; ni++) {
      const int rb = wc * 64 + ni * 16 + l15;
      bh[ni] = *(const half8*)&sB[p][0][rb][soff];
      bl[ni] = *(const half8*)&sB[p][1][rb][soff];
    }
#pragma unroll
    for (int mi = 0; mi < 4; mi++) {
      const int ra = wr * 64 + mi * 16 + l15;
      const half8 ah = *(const half8*)&sA[p][0][ra][soff];
      const half8 al = *(const half8*)&sA[p][1][ra][soff];
#pragma unroll
      for (int ni = 0; ni < 4; ni++) {
        acc[mi][ni] = MFMA16(ah, bh[ni], acc[mi][ni]);
        acc[mi][ni] = MFMA16(ah, bl[ni], acc[mi][ni]);
        acc[mi][ni] = MFMA16(al, bh[ni], acc[mi][ni]);
      }
    }
    if (more) {
      const int q = p ^ 1;
      *(half8*)&sA[q][0][m0][sp0 * 8] = rA0h;
      *(half8*)&sA[q][0][m1][sp0 * 8] = rA1h;
      *(half8*)&sA[q][1][m0][sp0 * 8] = rA0l;
      *(half8*)&sA[q][1][m1][sp0 * 8] = rA1l;
      *(half8*)&sB[q][0][m0][sp0 * 8] = rB0h;
      *(half8*)&sB[q][0][m1][sp0 * 8] = rB1h;
      *(half8*)&sB[q][1][m0][sp0 * 8] = rB0l;
      *(half8*)&sB[q][1][m1][sp0 * 8] = rB1l;
      __syncthreads();
      p = q;
    }
  }

  // epilogue: C row=(lane>>4)*4+reg, col=lane&15
  const float inv = 1.0f / 8192.0f;
  const int orow = bm + wr * 64 + (lane >> 4) * 4;
  const int ocol = bn + wc * 64 + l15;
#pragma unroll
  for (int ni = 0; ni < 4; ni++) {
    const int col = ocol + ni * 16;
    const float bv = bias[col];
#pragma unroll
    for (int mi = 0; mi < 4; mi++) {
      const f32x4 a = acc[mi][ni];
#pragma unroll
      for (int r = 0; r < 4; r++) {
        const size_t idx = (size_t)(orow + mi * 16 + r) * D_ + col;
        const float val = a[r] * inv + bv;
        if (f16out) {
          const float vs = val * 16.0f;            // scale 16 for attn MFMA
          const _Float16 hh = (_Float16)vs;
          Ch[idx] = hh;
          Cl[idx] = (_Float16)(vs - (float)hh);
        } else {
          Cf[idx] = val;
        }
      }
    }
  }
}

__global__ __launch_bounds__(256, 2) void gemm_qkv_f16(
    const _Float16* __restrict__ xh, const _Float16* __restrict__ xl,
    const _Float16* __restrict__ Whq, const _Float16* __restrict__ Wlq,
    const _Float16* __restrict__ Whk, const _Float16* __restrict__ Wlk,
    const _Float16* __restrict__ Whv, const _Float16* __restrict__ Wlv,
    const float* __restrict__ bq, const float* __restrict__ bk, const float* __restrict__ bv,
    _Float16* __restrict__ qh, _Float16* __restrict__ ql,
    _Float16* __restrict__ kh, _Float16* __restrict__ kl,
    float* __restrict__ vf) {
  const int z = blockIdx.z;
  const _Float16* Bh = (z == 0) ? Whq : (z == 1) ? Whk : Whv;
  const _Float16* Bl = (z == 0) ? Wlq : (z == 1) ? Wlk : Wlv;
  const float* bias = (z == 0) ? bq : (z == 1) ? bk : bv;
  if (z == 2) {
    gemm_f16x3_body(xh, xl, Bh, Bl, bias, vf, nullptr, nullptr, false);
  } else {
    _Float16* Ch = (z == 0) ? qh : kh;
    _Float16* Cl = (z == 0) ? ql : kl;
    gemm_f16x3_body(xh, xl, Bh, Bl, bias, nullptr, Ch, Cl, true);
  }
}

__global__ __launch_bounds__(256, 2) void gemm_out_f16(
    const _Float16* __restrict__ ah, const _Float16* __restrict__ al,
    const _Float16* __restrict__ bh, const _Float16* __restrict__ bl,
    const float* __restrict__ bias, float* __restrict__ C) {
  gemm_f16x3_body(ah, al, bh, bl, bias, C, nullptr, nullptr, false);
}

// ---------------- attention: MFMA QK^T + per-row top-k, latency-optimized ----------------
// Block = 512 thr (8 waves), owns 8 q-rows x one (b,h). One row per wave.
// R4 lesson: launch_bounds(512,8) forced VGPR=32 -> sc/e/fe arrays spilled to
// scratch -> 750 MB of spill traffic = the whole 424 us. This rev keeps ONLY
// sc[16] as live array state (e recomputed from sc; fe computed inline) and
// bounds at (512,4) (VGPR cap 128) so nothing can spill.
#define SSWZ(row) (((row) & 7) << 2)

__global__ __launch_bounds__(512, 4) void attn_topk_mfma(
    const _Float16* __restrict__ qh, const _Float16* __restrict__ ql,
    const _Float16* __restrict__ kh, const _Float16* __restrict__ kl,
    const float* __restrict__ vf,
    _Float16* __restrict__ awh, _Float16* __restrict__ awl) {
  __shared__ float S[8][1024];   // 32 KB
  __shared__ int   cidx[8][64];  // 2 KB   per-row candidate j list
  __shared__ float cfe[8][64];   // 2 KB   per-row candidate fe list
  const int t = threadIdx.x;
  const int lane = t & 63;
  const int w = t >> 6;              // 0..7, one q-row per wave
  const int i0 = blockIdx.x * 8;     // q-row tile
  const int h = blockIdx.y;
  const int b = blockIdx.z;
  const size_t rowbase = (size_t)b * L_;
  const int l15 = lane & 15;
  const int kgrp = lane >> 4;        // 0..3

  // ---- A-frags: rows i0 + (l15&7), duplicated over l15>=8
  half8 Ahf[2], Alf[2];
#pragma unroll
  for (int ks = 0; ks < 2; ks++) {
    const size_t off = (rowbase + i0 + (l15 & 7)) * D_ + h * DH_ + ks * 32 + kgrp * 8;
    Ahf[ks] = *(const half8*)(qh + off);
    Alf[ks] = *(const half8*)(ql + off);
  }

  // ---- QK^T: wave w covers j in [w*128, w*128+128)
  const float sscale = 1.0f / 2048.0f;  // 1/(16*16) * 1/sqrt(64)
  for (int jt = 0; jt < 8; jt++) {
    const int j0 = w * 128 + jt * 16;
    const size_t koff = (rowbase + j0 + l15) * D_ + h * DH_ + kgrp * 8;
    const half8 Bh0 = *(const half8*)(kh + koff);
    const half8 Bh1 = *(const half8*)(kh + koff + 32);
    const half8 Bl0 = *(const half8*)(kl + koff);
    const half8 Bl1 = *(const half8*)(kl + koff + 32);
    f32x4 acc = {0.f, 0.f, 0.f, 0.f};
    acc = MFMA16(Ahf[0], Bh0, acc);
    acc = MFMA16(Ahf[1], Bh1, acc);
    acc = MFMA16(Ahf[0], Bl0, acc);
    acc = MFMA16(Ahf[1], Bl1, acc);
    acc = MFMA16(Alf[0], Bh0, acc);
    acc = MFMA16(Alf[1], Bh1, acc);
    if (kgrp < 2) {
      const int srow = kgrp * 4;     // rows srow..srow+3 valid (0..7)
#pragma unroll
      for (int r = 0; r < 4; r++)
        S[srow + r][(j0 + l15) ^ SSWZ(srow + r)] = acc[r] * sscale;
    }
  }
  __syncthreads();

  // ---- selection: wave w owns row w
  const int row = w;
  const int swz = SSWZ(row);
  float sc[16];
#pragma unroll
  for (int u = 0; u < 16; u++) sc[u] = S[row][(u * 64 + lane) ^ swz];

  // ---- max
  float mx = sc[0];
#pragma unroll
  for (int u = 1; u < 16; u++) mx = fmaxf(mx, sc[u]);
#pragma unroll
  for (int off = 32; off >= 1; off >>= 1) mx = fmaxf(mx, __shfl_xor(mx, off, 64));

  // ---- bisection (window mx-16, 14 iters; exact descent below)
  float lo = mx - 16.f, hi = mx;
  for (int it = 0; it < 14; ++it) {
    float mid = 0.5f * (lo + hi);
    int cnt = 0;
#pragma unroll
    for (int u = 0; u < 16; u++) cnt += __popcll(__ballot(sc[u] >= mid));
    if (cnt >= 32) lo = mid; else hi = mid;
  }
  int cabove = 0;
#pragma unroll
  for (int u = 0; u < 16; u++) cabove += __popcll(__ballot(sc[u] >= hi));
  float v31 = hi;
  while (cabove < 32) {
    float nx = -INFINITY;
#pragma unroll
    for (int u = 0; u < 16; u++) nx = fmaxf(nx, (sc[u] < v31) ? sc[u] : -INFINITY);
#pragma unroll
    for (int off = 32; off >= 1; off >>= 1) nx = fmaxf(nx, __shfl_xor(nx, off, 64));
    int ceq = 0;
#pragma unroll
    for (int u = 0; u < 16; u++) ceq += __popcll(__ballot(sc[u] == nx));
    cabove += ceq;
    v31 = nx;
  }
  int c_eq = 0;
#pragma unroll
  for (int u = 0; u < 16; u++) c_eq += __popcll(__ballot(sc[u] == v31));
  const int c_gt = cabove - c_eq;
  const bool span = (cabove > 32);
  const int keep_eq = 32 - c_gt;
  float v32;
  if (span) {
    v32 = v31;
  } else {
    float nx = -INFINITY;
#pragma unroll
    for (int u = 0; u < 16; u++) nx = fmaxf(nx, (sc[u] < v31) ? sc[u] : -INFINITY);
#pragma unroll
    for (int off = 32; off >= 1; off >>= 1) nx = fmaxf(nx, __shfl_xor(nx, off, 64));
    v32 = nx;
  }
  const float tau = 0.5f * (v31 + v32);
  const float invbeta = 166666.67f;   // 1 / 6e-6

  // ---- z (e recomputed from sc; same order/values as storing e[16])
  float z = 0.f;
#pragma unroll
  for (int u = 0; u < 16; u++) z += __expf(sc[u] - mx);
#pragma unroll
  for (int off = 32; off >= 1; off >>= 1) z += __shfl_xor(z, off, 64);

  // sigmoid needed only if some score falls in the transition band
  // (|sc-tau| <= ~1.8e-4); outside it saturates exactly to 0/1.
  bool band = false;
  if (!span) {
    int inband = 0;
#pragma unroll
    for (int u = 0; u < 16; u++)
      inband |= (fabsf(sc[u] - tau) <= 1.81e-4f) ? 1 : 0;
    band = (__ballot(inband) != 0ull);
  }

  const float cutoff = fminf(tau - 1.8e-4f, v31);
  const float* vcol = vf + rowbase * D_ + h * DH_ + lane;
  float o;
  bool fast = false;
  if (!span) {
    // ---- compact candidates (j, fe) into LDS via ballot prefix
    int run = 0;
    float psum = 0.f;
#pragma unroll
    for (int u = 0; u < 16; u++) {
      unsigned long long m = __ballot(sc[u] >= cutoff);
      if (sc[u] >= cutoff) {
        const float eu = __expf(sc[u] - mx);
        float feu;
        if (band) {
          float arg = (sc[u] - tau) * invbeta;
          float fwv = (arg > 30.f) ? 1.f : ((arg < -30.f) ? 0.f : 1.f / (1.f + __expf(-arg)));
          feu = fwv * eu;
        } else {
          feu = (sc[u] > tau) ? eu : 0.f;
        }
        int pos = run + (int)__popcll(m & ((1ull << lane) - 1ull));
        if (pos < 64) { cidx[w][pos] = u * 64 + lane; cfe[w][pos] = feu; }
        psum += feu;
      }
      run += (int)__popcll(m);
    }
    if (run <= 64) {
      fast = true;
      float Ssum = psum;
#pragma unroll
      for (int off = 32; off >= 1; off >>= 1) Ssum += __shfl_xor(Ssum, off, 64);
      const int npad = (run + 7) & ~7;
      if (lane < npad - run) { cidx[w][run + lane] = 0; cfe[w][run + lane] = 0.f; }
      float acc = 0.f;
      for (int c = 0; c < npad; c += 8) {
        int jx[8]; float fx[8]; float vv[8];
#pragma unroll
        for (int i = 0; i < 8; i++) { jx[i] = cidx[w][c + i]; fx[i] = cfe[w][c + i]; }
#pragma unroll
        for (int i = 0; i < 8; i++) vv[i] = vcol[(size_t)jx[i] * D_];
#pragma unroll
        for (int i = 0; i < 8; i++) acc = fmaf(fx[i], vv[i], acc);
      }
      o = acc / (Ssum + 1e-8f * z);
    }
  }
  if (!fast) {
    // ---- exact original serial path (span ties / candidate overflow)
    float Ssum = 0.f, acc = 0.f;
    int eq_seen = 0;
    for (int u = 0; u < 16; ++u) {
      unsigned long long mask = __ballot(sc[u] >= cutoff);
      while (mask) {
        int l2 = (int)__builtin_ctzll(mask);
        mask &= mask - 1;
        float s_ = __shfl(sc[u], l2, 64);
        float e_ = __expf(s_ - mx);          // == shfl of e[u], bit-identical
        float f_;
        if (span) {
          if (s_ > v31) f_ = 1.f;
          else if (s_ == v31) { f_ = (eq_seen < keep_eq) ? 1.f : 0.f; ++eq_seen; }
          else f_ = 0.f;
        } else {
          float arg = (s_ - tau) * invbeta;
          f_ = (arg > 30.f) ? 1.f : ((arg < -30.f) ? 0.f : 1.f / (1.f + __expf(-arg)));
        }
        float fe_ = f_ * e_;
        Ssum += fe_;
        acc = fmaf(fe_, vcol[(size_t)(u * 64 + l2) * D_], acc);
      }
    }
    o = acc / (Ssum + 1e-8f * z);
  }

  const float os = o * 16.0f;                  // scale 16 for the f16x3 out-GEMM
  const _Float16 oh = (_Float16)os;
  const size_t oidx = (rowbase + i0 + row) * D_ + h * DH_ + lane;
  awh[oidx] = oh;
  awl[oidx] = (_Float16)(os - (float)oh);
}

extern "C" void kernel_launch(void* const* d_in, const int* in_sizes, int n_in,
                              void* d_out, int out_size, void* d_ws, size_t ws_size,
                              hipStream_t stream) {
  const float* x  = (const float*)d_in[0];
  const float* Wq = (const float*)d_in[1];
  const float* bq = (const float*)d_in[2];
  const float* Wk = (const float*)d_in[3];
  const float* bk = (const float*)d_in[4];
  const float* Wv = (const float*)d_in[5];
  const float* bv = (const float*)d_in[6];
  const float* Wo = (const float*)d_in[7];
  const float* bo = (const float*)d_in[8];
  float* out = (float*)d_out;

  const size_t MD = (size_t)M_ * D_;   // 4M elements
  const size_t WD = (size_t)D_ * D_;   // 1M elements
  float* slot0 = (float*)d_ws;
  float* slot1 = slot0 + MD;
  float* vf    = slot1 + MD;
  float* slot3 = vf + MD;
  float* slot4 = slot3 + MD;

  _Float16* qh = (_Float16*)slot0;  _Float16* ql = qh + MD;
  _Float16* kh = (_Float16*)slot1;  _Float16* kl = kh + MD;
  _Float16* xh = (_Float16*)slot3;  _Float16* xl = xh + MD;
  _Float16* awh = xh;               // alias: xh/xl dead after gemm_qkv
  _Float16* awl = xl;
  _Float16* Whq = (_Float16*)slot4;
  _Float16* Wlq = Whq + WD;
  _Float16* Whk = Wlq + WD;
  _Float16* Wlk = Whk + WD;
  _Float16* Whv = Wlk + WD;
  _Float16* Wlv = Whv + WD;
  _Float16* Who = Wlv + WD;
  _Float16* Wlo = Who + WD;

  dim3 b256(256);
  hipLaunchKernelGGL(split_x, dim3(4096), b256, 0, stream, x, xh, xl);
  hipLaunchKernelGGL(split_wt, dim3(256), b256, 0, stream, Wq, Whq, Wlq);
  hipLaunchKernelGGL(split_wt, dim3(256), b256, 0, stream, Wk, Whk, Wlk);
  hipLaunchKernelGGL(split_wt, dim3(256), b256, 0, stream, Wv, Whv, Wlv);
  hipLaunchKernelGGL(split_wt, dim3(256), b256, 0, stream, Wo, Who, Wlo);
  hipLaunchKernelGGL(gemm_qkv_f16, dim3(8, 32, 3), b256, 0, stream,
                     xh, xl, Whq, Wlq, Whk, Wlk, Whv, Wlv, bq, bk, bv,
                     qh, ql, kh, kl, vf);
  hipLaunchKernelGGL(attn_topk_mfma, dim3(128, 16, 4), dim3(512), 0, stream,
                     qh, ql, kh, kl, vf, awh, awl);
  hipLaunchKernelGGL(gemm_out_f16, dim3(8, 32), b256, 0, stream,
                     awh, awl, Who, Wlo, bo, out);
}